// Round 13
// baseline (113.569 us; speedup 1.0000x reference)
//
#include <hip/hip_runtime.h>
#include <stdint.h>

#define NN 8192
#define KD 512
#define BM 128
#define BK 32
#define NTILE (NN / BM)                 // 64
#define NTRI (NTILE * (NTILE + 1) / 2)  // 2080
#define NPAIR (NTRI / 2)                // 1040
#define NKT (KD / BK)                   // 16

typedef __bf16 bf16;
typedef __bf16 bf16x8 __attribute__((ext_vector_type(8)));
typedef float f32x4 __attribute__((ext_vector_type(4)));

// ---------------- kernel 1: row L2-normalize, fp32 -> bf16 ----------------
__global__ __launch_bounds__(256) void rownorm_kernel(const float* __restrict__ proto,
                                                      bf16* __restrict__ pn) {
    const int row  = blockIdx.x * 4 + (threadIdx.x >> 6);
    const int lane = threadIdx.x & 63;
    const float4* src = (const float4*)(proto + (size_t)row * KD) + lane * 2;
    const float4 v0 = src[0];
    const float4 v1 = src[1];
    float s = v0.x*v0.x + v0.y*v0.y + v0.z*v0.z + v0.w*v0.w
            + v1.x*v1.x + v1.y*v1.y + v1.z*v1.z + v1.w*v1.w;
#pragma unroll
    for (int off = 32; off; off >>= 1) s += __shfl_xor(s, off);
    const float inv = 1.0f / fmaxf(sqrtf(s), 1e-12f);
    bf16x8 o;
    o[0] = (bf16)(v0.x*inv); o[1] = (bf16)(v0.y*inv);
    o[2] = (bf16)(v0.z*inv); o[3] = (bf16)(v0.w*inv);
    o[4] = (bf16)(v1.x*inv); o[5] = (bf16)(v1.y*inv);
    o[6] = (bf16)(v1.z*inv); o[7] = (bf16)(v1.w*inv);
    *(bf16x8*)(pn + (size_t)row * KD + lane * 8) = o;
}

// -- kernel 2: paired tiles; tile0 stores hidden under tile1 K-loop --------
__device__ __forceinline__ void gload_lds16(const bf16* g, bf16* l) {
    __builtin_amdgcn_global_load_lds(
        (const __attribute__((address_space(1))) void*)g,
        (__attribute__((address_space(3))) void*)l, 16, 0, 0);
}

__device__ __forceinline__ float lrelu(float v) {
    return (v >= 0.0f) ? v : 0.01f * v;
}

__global__ __launch_bounds__(256, 3) void gemm_sym_pair_kernel(const bf16* __restrict__ P,
                                                               float* __restrict__ C) {
    // overlay: staging 32 KB / sE [64][129] 33.0 KB / sM [128][65] 33.3 KB
    __shared__ __align__(16) unsigned char smem[33280];
    bf16*  sA = (bf16*)smem;               // [2][4096]
    bf16*  sB = (bf16*)(smem + 16384);     // [2][4096]
    float* sE = (float*)smem;              // [64][129]
    float* sM = (float*)smem;              // [128][65]

    // pair-level bijective XCD swizzle: 1040 = 8 x 130
    const int bid  = blockIdx.x;
    const int swzp = (bid & 7) * (NPAIR / 8) + (bid >> 3);
    const int s0   = swzp * 2;
    int tm0 = 0, rem = s0;
    while (rem >= NTILE - tm0) { rem -= NTILE - tm0; ++tm0; }
    const int tn0 = tm0 + rem;
    const int tm1 = (tn0 + 1 < NTILE) ? tm0 : tm0 + 1;
    const int tn1 = (tn0 + 1 < NTILE) ? tn0 + 1 : tm0 + 1;

    const int tid  = threadIdx.x;
    const int w    = tid >> 6;
    const int lane = tid & 63;
    const int wm = (w >> 1) * 64;
    const int wn = (w & 1) * 64;
    const int rr = lane & 15;
    const int h  = lane >> 4;
    const int cr = h * 4;
    const int cc = rr;

    const int rowA0 = tm0 * BM, rowB0 = tn0 * BM;
    const int rowA1 = tm1 * BM, rowB1 = tn1 * BM;

    const int chunk0 = w * 128 + lane;
    const bf16* g0 = P + (size_t)(chunk0 >> 2) * KD + (chunk0 & 3) * 8;
    const size_t offA0 = (size_t)rowA0 * KD, offB0 = (size_t)rowB0 * KD;
    const size_t offA1 = (size_t)rowA1 * KD, offB1 = (size_t)rowB1 * KD;
    const int ldsOff0 = w * 1024;
    const int ldsOff1 = w * 1024 + 512;

#define VMCNT(n) asm volatile("s_waitcnt vmcnt(" #n ")" ::: "memory")

// LDS-drain fence: my ds_reads delivered (lgkmcnt 0), pinned against MFMA
// sink/hoist (rule #18: sched_barrier after the wait), then barrier.
// Does NOT touch vmcnt -> staged loads + lazy stores stay in flight.
#define LDS_FENCE_BAR()                                               \
    do {                                                              \
        asm volatile("s_waitcnt lgkmcnt(0)" ::: "memory");            \
        __builtin_amdgcn_sched_barrier(0);                            \
        __builtin_amdgcn_s_barrier();                                 \
    } while (0)

#define STAGEX(buf, kt, oA, oB)                                               \
    do {                                                                      \
        gload_lds16(g0 + (oA) + (kt),           sA + (buf) * 4096 + ldsOff0); \
        gload_lds16(g0 + (oA) + 16 * KD + (kt), sA + (buf) * 4096 + ldsOff1); \
        gload_lds16(g0 + (oB) + (kt),           sB + (buf) * 4096 + ldsOff0); \
        gload_lds16(g0 + (oB) + 16 * KD + (kt), sB + (buf) * 4096 + ldsOff1); \
    } while (0)

#define COMPUTEX(buf, accv)                                                   \
    do {                                                                      \
        const bf16* ra_ = sA + (buf) * 4096;                                  \
        const bf16* rb_ = sB + (buf) * 4096;                                  \
        bf16x8 af[4], bfr[4];                                                 \
        _Pragma("unroll")                                                     \
        for (int m = 0; m < 4; ++m)                                           \
            af[m] = *(const bf16x8*)(ra_ + (wm + m * 16 + rr) * 32 + h * 8);  \
        _Pragma("unroll")                                                     \
        for (int n = 0; n < 4; ++n)                                           \
            bfr[n] = *(const bf16x8*)(rb_ + (wn + n * 16 + rr) * 32 + h * 8); \
        _Pragma("unroll")                                                     \
        for (int m = 0; m < 4; ++m)                                           \
            _Pragma("unroll")                                                 \
            for (int n = 0; n < 4; ++n)                                       \
                accv[m][n] = __builtin_amdgcn_mfma_f32_16x16x32_bf16(         \
                    af[m], bfr[n], accv[m][n], 0, 0, 0);                      \
    } while (0)

    // ================= tile 0: proven dbuf K-loop (__syncthreads) =========
    f32x4 acc0[4][4] = {};
    STAGEX(0, 0, offA0, offB0);
    __syncthreads();
#pragma unroll
    for (int t = 0; t < NKT; ++t) {
        if (t < NKT - 1) STAGEX((t + 1) & 1, (t + 1) * BK, offA0, offB0);
        COMPUTEX(t & 1, acc0);
        if (t < NKT - 1) __syncthreads();
    }

    // ================= tile 1 K-loop with tile0 stores hidden =============
    f32x4 acc1[4][4] = {};
    STAGEX(0, 0, offA1, offB1);          // loads(0); buf0 (compute(15) used buf1)
    LDS_FENCE_BAR();                     // compute(15) ds_reads delivered

#pragma unroll
    for (int t = 0; t < NKT; ++t) {
        if (t < NKT - 1) STAGEX((t + 1) & 1, (t + 1) * BK, offA1, offB1);
        // counted ledger (in-order vmcnt): at entry queue =
        //   [loads(t) (4), stores(t-1) (5), loads(t+1) (4)]
        // guarantee loads(t) retired; stores drain lazily, never vmcnt(0).
        if (t == 0)            VMCNT(4);
        else if (t < NKT - 1)  VMCNT(9);
        else                   VMCNT(5);
        __builtin_amdgcn_s_barrier();
        COMPUTEX(t & 1, acc1);
        // 5 tile0 stores per iter (4 direct + 1 mirror f32x4)
        {
            const int m = t >> 2, r = t & 3;
#pragma unroll
            for (int n = 0; n < 4; ++n)
                C[(size_t)(rowA0 + wm + m * 16 + cr + r) * NN
                  + (rowB0 + wn + n * 16 + cc)] = lrelu(acc0[m][n][r]);
            const int mm = t & 3, nn = t >> 2;
            f32x4 mv;
            mv[0] = lrelu(acc0[mm][nn][0]);
            mv[1] = lrelu(acc0[mm][nn][1]);
            mv[2] = lrelu(acc0[mm][nn][2]);
            mv[3] = lrelu(acc0[mm][nn][3]);
            *(f32x4*)&C[(size_t)(rowB0 + wn + nn * 16 + cc) * NN
                        + (rowA0 + wm + mm * 16 + cr)] = mv;
        }
        // WAR fence: compute(t)'s ds_reads of buf[t&1] must deliver before
        // iter t+1's STAGEX(t+2) overwrites it. lgkm drain, NOT vmcnt.
        if (t < NKT - 1) LDS_FENCE_BAR();
    }

    // ================= tile 1 epilogue: full-line LDS-staged ==============
    const int wr = w >> 1;
#pragma unroll
    for (int H = 0; H < 2; ++H) {
        LDS_FENCE_BAR();
        if (wr == H) {
#pragma unroll
            for (int m = 0; m < 4; ++m)
#pragma unroll
                for (int n = 0; n < 4; ++n)
#pragma unroll
                    for (int r = 0; r < 4; ++r)
                        sE[(m * 16 + cr + r) * 129 + wn + n * 16 + cc] =
                            lrelu(acc1[m][n][r]);
        }
        LDS_FENCE_BAR();
#pragma unroll
        for (int k = 0; k < 8; ++k) {
            const int seg = tid + k * 256;
            const int lr  = seg >> 5;
            const int c4  = (seg & 31) * 4;
            const f32x4 v = *(const f32x4*)&sE[lr * 129 + c4];
            *(f32x4*)&C[(size_t)(rowA1 + H * 64 + lr) * NN + rowB1 + c4] = v;
        }
        LDS_FENCE_BAR();
        if (wr == H) {
#pragma unroll
            for (int m = 0; m < 4; ++m)
#pragma unroll
                for (int n = 0; n < 4; ++n) {
                    f32x4 tv;
                    tv[0] = lrelu(acc1[m][n][0]);
                    tv[1] = lrelu(acc1[m][n][1]);
                    tv[2] = lrelu(acc1[m][n][2]);
                    tv[3] = lrelu(acc1[m][n][3]);
                    *(f32x4*)&sM[(wn + n * 16 + cc) * 65 + m * 16 + cr] = tv;
                }
        }
        LDS_FENCE_BAR();
        if (tm1 != tn1) {
#pragma unroll
            for (int rd = 0; rd < 8; ++rd) {
                const int j  = (tid >> 4) + rd * 16;
                const int i0 = (tid & 15) * 4;
                const f32x4 v = *(const f32x4*)&sM[j * 65 + i0];
                *(f32x4*)&C[(size_t)(rowB1 + j) * NN + rowA1 + H * 64 + i0] = v;
            }
        }
    }
#undef STAGEX
#undef COMPUTEX
#undef VMCNT
#undef LDS_FENCE_BAR
}

extern "C" void kernel_launch(void* const* d_in, const int* in_sizes, int n_in,
                              void* d_out, int out_size, void* d_ws, size_t ws_size,
                              hipStream_t stream) {
    const float* proto = (const float*)d_in[1];
    float* C  = (float*)d_out;
    bf16* pn  = (bf16*)d_ws;   // 8 MB scratch

    rownorm_kernel<<<dim3(NN / 4), dim3(256), 0, stream>>>(proto, pn);
    gemm_sym_pair_kernel<<<dim3(NPAIR), dim3(256), 0, stream>>>(pn, C);
}

// Round 14
// 93.470 us; speedup vs baseline: 1.2150x; 1.2150x over previous
//
#include <hip/hip_runtime.h>
#include <stdint.h>

#define NN 8192
#define KD 512
#define BM 128
#define BK 32
#define NTILE (NN / BM)                 // 64
#define NTRI (NTILE * (NTILE + 1) / 2)  // 2080
#define NKT (KD / BK)                   // 16

typedef __bf16 bf16;
typedef __bf16 bf16x8 __attribute__((ext_vector_type(8)));
typedef float f32x4 __attribute__((ext_vector_type(4)));

// ---------------- kernel 1: row L2-normalize, fp32 -> bf16 ----------------
__global__ __launch_bounds__(256) void rownorm_kernel(const float* __restrict__ proto,
                                                      bf16* __restrict__ pn) {
    const int row  = blockIdx.x * 4 + (threadIdx.x >> 6);
    const int lane = threadIdx.x & 63;
    const float4* src = (const float4*)(proto + (size_t)row * KD) + lane * 2;
    const float4 v0 = src[0];
    const float4 v1 = src[1];
    float s = v0.x*v0.x + v0.y*v0.y + v0.z*v0.z + v0.w*v0.w
            + v1.x*v1.x + v1.y*v1.y + v1.z*v1.z + v1.w*v1.w;
#pragma unroll
    for (int off = 32; off; off >>= 1) s += __shfl_xor(s, off);
    const float inv = 1.0f / fmaxf(sqrtf(s), 1e-12f);
    bf16x8 o;
    o[0] = (bf16)(v0.x*inv); o[1] = (bf16)(v0.y*inv);
    o[2] = (bf16)(v0.z*inv); o[3] = (bf16)(v0.w*inv);
    o[4] = (bf16)(v1.x*inv); o[5] = (bf16)(v1.y*inv);
    o[6] = (bf16)(v1.z*inv); o[7] = (bf16)(v1.w*inv);
    *(bf16x8*)(pn + (size_t)row * KD + lane * 8) = o;
}

// -- kernel 2: C = leakyrelu(P P^T), symmetric, LDS-staged full-line writes -
__device__ __forceinline__ void gload_lds16(const bf16* g, bf16* l) {
    __builtin_amdgcn_global_load_lds(
        (const __attribute__((address_space(1))) void*)g,
        (__attribute__((address_space(3))) void*)l, 16, 0, 0);
}

__device__ __forceinline__ float lrelu(float v) {
    return (v >= 0.0f) ? v : 0.01f * v;
}

__global__ __launch_bounds__(256, 4) void gemm_sym_kernel(const bf16* __restrict__ P,
                                                          float* __restrict__ C) {
    // overlay: K-loop staging (32 KB) and epilogue buffer [64][129] f32 (33 KB)
    __shared__ __align__(16) unsigned char smem[33024];
    bf16*  sA = (bf16*)smem;               // [2][4096] elems
    bf16*  sB = (bf16*)(smem + 16384);     // [2][4096] elems
    float* sE = (float*)smem;              // [64][129]

    // bijective XCD swizzle: 2080 = 8 x 260
    const int bid = blockIdx.x;
    const int swz = (bid & 7) * (NTRI / 8) + (bid >> 3);
    int tm = 0, rem = swz;
    while (rem >= NTILE - tm) { rem -= NTILE - tm; ++tm; }
    const int tn = tm + rem;

    const int tid  = threadIdx.x;
    const int w    = tid >> 6;
    const int lane = tid & 63;
    const int wr = w >> 1;               // wave row 0..1 -> rows wr*64..+63
    const int rowA0 = tm * BM;
    const int rowB0 = tn * BM;
    const int wm = wr * 64;
    const int wn = (w & 1) * 64;
    const int rr = lane & 15;
    const int h  = lane >> 4;

    // staging: wave w covers rows w*32..w*32+31 (two 16-row slots)
    const int chunk0 = w * 128 + lane;
    const bf16* g0 = P + (size_t)(chunk0 >> 2) * KD + (chunk0 & 3) * 8;
    const size_t offA = (size_t)rowA0 * KD;
    const size_t offB = (size_t)rowB0 * KD;
    const int ldsOff0 = w * 1024;
    const int ldsOff1 = w * 1024 + 512;

    f32x4 acc[4][4] = {};

#define STAGE(buf, kt)                                                        \
    do {                                                                      \
        gload_lds16(g0 + offA + (kt),           sA + (buf) * 4096 + ldsOff0); \
        gload_lds16(g0 + offA + 16 * KD + (kt), sA + (buf) * 4096 + ldsOff1); \
        gload_lds16(g0 + offB + (kt),           sB + (buf) * 4096 + ldsOff0); \
        gload_lds16(g0 + offB + 16 * KD + (kt), sB + (buf) * 4096 + ldsOff1); \
    } while (0)

#define COMPUTE(buf)                                                          \
    do {                                                                      \
        const bf16* ra_ = sA + (buf) * 4096;                                  \
        const bf16* rb_ = sB + (buf) * 4096;                                  \
        bf16x8 af[4], bfr[4];                                                 \
        _Pragma("unroll")                                                     \
        for (int m = 0; m < 4; ++m)                                           \
            af[m] = *(const bf16x8*)(ra_ + (wm + m * 16 + rr) * 32 + h * 8);  \
        _Pragma("unroll")                                                     \
        for (int n = 0; n < 4; ++n)                                           \
            bfr[n] = *(const bf16x8*)(rb_ + (wn + n * 16 + rr) * 32 + h * 8); \
        _Pragma("unroll")                                                     \
        for (int m = 0; m < 4; ++m)                                           \
            _Pragma("unroll")                                                 \
            for (int n = 0; n < 4; ++n)                                       \
                acc[m][n] = __builtin_amdgcn_mfma_f32_16x16x32_bf16(          \
                    af[m], bfr[n], acc[m][n], 0, 0, 0);                       \
    } while (0)

    // prologue: tile 0 -> buf 0
    STAGE(0, 0);
    __syncthreads();

    // dbuf: stage t+1, compute t, one barrier per K-tile (R4 structure)
#pragma unroll
    for (int t = 0; t < NKT; ++t) {
        if (t < NKT - 1) STAGE((t + 1) & 1, (t + 1) * BK);
        COMPUTE(t & 1);
        if (t < NKT - 1) __syncthreads();
    }

    // ---- LDS-staged epilogue: two 64-row halves, full-line stores ----
    const int cr = h * 4;            // acc reg r -> local row cr+r
    const int cc = rr;               // local col within wave's 64-col strip

#pragma unroll
    for (int H = 0; H < 2; ++H) {
        __syncthreads();   // K-loop reads done (H=0) / prev half reads done (H=1)
        if (wr == H) {
#pragma unroll
            for (int m = 0; m < 4; ++m)
#pragma unroll
                for (int n = 0; n < 4; ++n)
#pragma unroll
                    for (int r = 0; r < 4; ++r)
                        sE[(m * 16 + cr + r) * 129 + wn + n * 16 + cc] =
                            lrelu(acc[m][n][r]);
        }
        __syncthreads();

        // direct: rows rowA0+H*64+lr, 128 cols; 32 lanes = 512B/row (4 lines)
#pragma unroll
        for (int k = 0; k < 8; ++k) {
            const int seg = tid + k * 256;
            const int lr  = seg >> 5;
            const int c4  = (seg & 31) * 4;
            const float4 v = *(const float4*)&sE[lr * 129 + c4];
            *(float4*)&C[(size_t)(rowA0 + H * 64 + lr) * NN + rowB0 + c4] = v;
        }

        // mirror (off-diag): row j = tile col; transposed LDS read (2-way banks)
        if (tm != tn) {
#pragma unroll
            for (int rd = 0; rd < 8; ++rd) {
                const int j = (tid >> 4) + rd * 16;
                const int i0 = (tid & 15) * 4;
                float4 v;
                v.x = sE[(i0 + 0) * 129 + j];
                v.y = sE[(i0 + 1) * 129 + j];
                v.z = sE[(i0 + 2) * 129 + j];
                v.w = sE[(i0 + 3) * 129 + j];
                *(float4*)&C[(size_t)(rowB0 + j) * NN + rowA0 + H * 64 + i0] = v;
            }
        }
    }
#undef STAGE
#undef COMPUTE
}

extern "C" void kernel_launch(void* const* d_in, const int* in_sizes, int n_in,
                              void* d_out, int out_size, void* d_ws, size_t ws_size,
                              hipStream_t stream) {
    const float* proto = (const float*)d_in[1];
    float* C  = (float*)d_out;
    bf16* pn  = (bf16*)d_ws;   // 8 MB scratch

    rownorm_kernel<<<dim3(NN / 4), dim3(256), 0, stream>>>(proto, pn);
    gemm_sym_kernel<<<dim3(NTRI), dim3(256), 0, stream>>>(pn, C);
}